// Round 7
// baseline (130.428 us; speedup 1.0000x reference)
//
#include <hip/hip_runtime.h>
#include <stdint.h>
#include <stddef.h>

typedef __bf16 bf16;
typedef __bf16 bf16x8 __attribute__((ext_vector_type(8)));
typedef float f32x4 __attribute__((ext_vector_type(4)));
typedef unsigned int uint32x2 __attribute__((ext_vector_type(2)));
typedef unsigned int uint32x4 __attribute__((ext_vector_type(4)));

typedef const __attribute__((address_space(1))) uint32_t GU32;
typedef __attribute__((address_space(3))) uint32_t LU32;

__device__ __forceinline__ f32x4 mfma16(bf16x8 a, bf16x8 b, f32x4 c) {
  return __builtin_amdgcn_mfma_f32_16x16x32_bf16(a, b, c, 0, 0, 0);
}
__device__ __forceinline__ void gload16(const void* g, void* l) {
  __builtin_amdgcn_global_load_lds((GU32*)g, (LU32*)l, 16, 0, 0);
}

// ---------------- prep: W_Q|W_K|W_V (f32 [2048][128]) -> WA bf16 in gload-linear
// fragment order: granule[ks][ng][kk][l16][l15] = W[k=ks*64+kk*32+l16*8+(0..7)][n=ng*16+l15]
// Grid 192 = 3 matrices x 32 k-tiles x 2 n-tiles; 64x64 LDS transpose tiles.
__global__ __launch_bounds__(256) void k_prep(const float* __restrict__ Wq,
                                              const float* __restrict__ Wk,
                                              const float* __restrict__ Wv,
                                              bf16* __restrict__ WA) {
  __shared__ float tile[64][65];
  const int tid = threadIdx.x;
  const int widx = blockIdx.x >> 6, rem = blockIdx.x & 63;
  const int k0 = (rem >> 1) * 64, n0 = (rem & 1) * 64;
  const float* W = (widx == 0) ? Wq : (widx == 1) ? Wk : Wv;
  const int rg = tid >> 4, cq = tid & 15;
#pragma unroll
  for (int i = 0; i < 4; ++i) {
    int krow = i * 16 + rg;
    f32x4 v = *(const f32x4*)(W + (size_t)(k0 + krow) * 128 + n0 + cq * 4);
#pragma unroll
    for (int j = 0; j < 4; ++j) tile[krow][cq * 4 + j] = v[j];
  }
  __syncthreads();
#pragma unroll
  for (int gi = 0; gi < 2; ++gi) {
    int G = tid * 2 + gi;                 // 0..511 granules of this 64x64 tile
    int n_local = G >> 3, kg = G & 7;
    union { bf16 h[8]; uint32x4 u; } pk;
#pragma unroll
    for (int j = 0; j < 8; ++j) pk.h[j] = (bf16)tile[kg * 8 + j][n_local];
    int n_glob = widx * 128 + n0 + n_local;
    int k_glob = k0 + kg * 8;
    int ks = k_glob >> 6, kl = k_glob & 63;
    int kk = kl >> 5, l16g = (kl >> 3) & 3;
    int ng = n_glob >> 4, l15g = n_glob & 15;
    size_t gaddr = (size_t)ks * 3072 + (size_t)((ng * 2 + kk) * 64 + l16g * 16 + l15g);
    *(uint32x4*)((uint8_t*)WA + gaddr * 16) = pk.u;
  }
}

// ---------------- projection GEMM + RoPE epilogue ----------------
// x f32 [16384][2048] @ W^T -> Q,K (RoPE, bf16 [b][s][128]) and Vt (bf16 [b][128][4096])
// BM=64, BN=384. Grid 256, 512 threads (8 waves). All staging LINEAR (coalesced,
// conflict-free): B via fragment-ordered WA + gload_lds; A reg-staged, 17/68-pad LDS.
__global__ __launch_bounds__(512, 1) void k_proj(
    const float* __restrict__ x, const float* __restrict__ sint, const float* __restrict__ cost,
    const bf16* __restrict__ WA, bf16* __restrict__ Qg, bf16* __restrict__ Kg,
    bf16* __restrict__ Vtg) {
  __shared__ __align__(16) uint8_t smem[115712];  // A0@0(8704) A1@8704 B0@17408(49152) B1@66560
  const int tid = threadIdx.x;
  const int lane = tid & 63, w = tid >> 6;
  const int l15 = lane & 15, l16 = lane >> 4;
  const int mb = blockIdx.x;
  const int arow = tid >> 3, aj = tid & 7;   // A staging: row 0..63, 8-float chunk 0..7

  f32x4 acc[4][3] = {};
  f32x4 regA[2], regB[2];

  const float* abase = x + (size_t)(mb * 64 + arow) * 2048 + aj * 8;
  const uint8_t* wbase = (const uint8_t*)WA;
  const int agw = ((arow >> 4) * 2 + (aj >> 2)) * 68 + (aj & 3) * 17 + (arow & 15);

  auto stageB = [&](int buf, int ks) {
    uint8_t* bbm = smem + 17408 + buf * 49152;
    const uint8_t* src = wbase + (size_t)ks * 49152 + tid * 16;
#pragma unroll
    for (int i = 0; i < 6; ++i)
      gload16(src + i * 8192, bbm + i * 8192 + tid * 16);
  };
  auto loadA = [&](int ks, f32x4* r) {
    const f32x4* p = (const f32x4*)(abase + ks * 64);
    r[0] = p[0];
    r[1] = p[1];
  };
  auto writeA = [&](int buf, const f32x4* r) {
    uint8_t* ab = smem + buf * 8704;
    union { bf16 v[8]; uint32x4 u; } pk;
#pragma unroll
    for (int e = 0; e < 8; ++e) pk.v[e] = (bf16)r[e >> 2][e & 3];
    *(uint32x4*)(ab + (agw << 4)) = pk.u;
  };
  auto compute = [&](int buf) {
    uint8_t* ab = smem + buf * 8704;
    uint8_t* bbm = smem + 17408 + buf * 49152;
    bf16x8 af[2][4], bv[2][3];
#pragma unroll
    for (int kk = 0; kk < 2; ++kk) {
#pragma unroll
      for (int mt = 0; mt < 4; ++mt)
        af[kk][mt] = *(const bf16x8*)(ab + (((mt * 2 + kk) * 68 + l16 * 17 + l15) << 4));
#pragma unroll
      for (int nt = 0; nt < 3; ++nt)
        bv[kk][nt] = *(const bf16x8*)(bbm + ((((w * 3 + nt) * 2 + kk) << 10) + lane * 16));
    }
    __builtin_amdgcn_s_setprio(1);
#pragma unroll
    for (int kk = 0; kk < 2; ++kk)
#pragma unroll
      for (int mt = 0; mt < 4; ++mt)
#pragma unroll
        for (int nt = 0; nt < 3; ++nt)
          acc[mt][nt] = mfma16(af[kk][mt], bv[kk][nt], acc[mt][nt]);
    __builtin_amdgcn_s_setprio(0);
  };

  // prologue: LDS[0] <- B(0), A(0); A(1) stays in flight
  loadA(0, regA);
  stageB(0, 0);
  loadA(1, regB);
  writeA(0, regA);
  asm volatile("s_waitcnt vmcnt(2)" ::: "memory");   // B(0) landed; A(1) in flight
  asm volatile("s_waitcnt lgkmcnt(0)" ::: "memory");
  __builtin_amdgcn_s_barrier();

  for (int ks = 0; ks < 30; ks += 2) {
    {
      stageB(1, ks + 1);
      loadA(ks + 2, regA);
      compute(0);
      writeA(1, regB);
      asm volatile("s_waitcnt vmcnt(2)" ::: "memory");
      asm volatile("s_waitcnt lgkmcnt(0)" ::: "memory");
      __builtin_amdgcn_s_barrier();
    }
    {
      stageB(0, ks + 2);
      loadA(ks + 3, regB);
      compute(1);
      writeA(0, regA);
      asm volatile("s_waitcnt vmcnt(2)" ::: "memory");
      asm volatile("s_waitcnt lgkmcnt(0)" ::: "memory");
      __builtin_amdgcn_s_barrier();
    }
  }
  {
    stageB(1, 31);
    compute(0);
    writeA(1, regB);
    asm volatile("s_waitcnt vmcnt(0)" ::: "memory");
    asm volatile("s_waitcnt lgkmcnt(0)" ::: "memory");
    __builtin_amdgcn_s_barrier();
  }
  compute(1);

  // epilogue: RoPE for Q/K columns, transpose-store for V
  const int bb = mb >> 6;
#pragma unroll
  for (int mt = 0; mt < 4; ++mt) {
    int gm = mb * 64 + mt * 16 + l16 * 4;
    int s0 = gm & 4095;
#pragma unroll
    for (int nt = 0; nt < 3; ++nt) {
      int jcol = w * 48 + nt * 16 + l15;
      f32x4 v = acc[mt][nt];
      if (jcol < 256) {
        int p = (jcol & 127) >> 1;
        bool even = ((jcol & 1) == 0);
#pragma unroll
        for (int r = 0; r < 4; ++r) {
          float pv = __shfl_xor(v[r], 1);
          int s = s0 + r;
          float cs = cost[s * 64 + p], sn = sint[s * 64 + p];
          float nv = even ? (v[r] * cs - pv * sn) : (v[r] * cs + pv * sn);
          bf16 hb = (bf16)nv;
          if (jcol < 128) Qg[((size_t)(bb << 12) + s) * 128 + jcol] = hb;
          else            Kg[((size_t)(bb << 12) + s) * 128 + jcol - 128] = hb;
        }
      } else {
        int d = jcol - 256;
        union { bf16 h[4]; uint32x2 u; } pk;
#pragma unroll
        for (int r = 0; r < 4; ++r) pk.h[r] = (bf16)v[r];
        *(uint32x2*)((uint8_t*)Vtg + (((size_t)(bb << 7) + d) * 4096 + s0) * 2) = pk.u;
      }
    }
  }
}

// ---------------- flash attention partials (KV-chunked causal) ----------------
// grid: 320 blocks = 4 batches x {j(0..31) x chunks(1+j/8)}; block = 4 waves x 32 q-rows
__global__ __launch_bounds__(256, 2) void k_attn(
    const bf16* __restrict__ Qg, const bf16* __restrict__ Kg, const bf16* __restrict__ Vtg,
    float* __restrict__ PO, float* __restrict__ ML) {
  __shared__ __align__(16) uint8_t smem[81920];  // [2] x (K 16K | V 16K) + 4 x P 4K
  const int tid = threadIdx.x;
  const int lane = tid & 63, w = tid >> 6;
  const int l15 = lane & 15, l16 = lane >> 4;

  int gid = blockIdx.x;
  int b = gid / 80, rr = gid % 80;
  int j, c;
  if (rr < 8)       { j = rr;                 c = 0; }
  else if (rr < 24) { j = 8 + ((rr - 8) >> 1);  c = (rr - 8) & 1; }
  else if (rr < 48) { j = 16 + (rr - 24) / 3;   c = (rr - 24) % 3; }
  else              { j = 24 + ((rr - 48) >> 2); c = (rr - 48) & 3; }

  const int q0w = j * 128 + w * 32;
  const int kv_lo = c * 1024;
  const int kv_hi = min((c + 1) * 1024, (j + 1) * 128);
  const int T = (kv_hi - kv_lo) >> 6;

  bf16x8 qf[2][4];
#pragma unroll
  for (int qt = 0; qt < 2; ++qt)
#pragma unroll
    for (int kk = 0; kk < 4; ++kk)
      qf[qt][kk] = *(const bf16x8*)(Qg + ((size_t)(b << 12) + q0w + qt * 16 + l15) * 128 + kk * 32 + l16 * 8);

  f32x4 o[2][8] = {};
  float m_r[2] = {-1e30f, -1e30f};
  float l_r[2] = {0.f, 0.f};
  uint8_t* pb = smem + 65536 + w * 4096;

  auto stage = [&](int t) {
    uint8_t* kb = smem + (t & 1) * 32768;
    uint8_t* vb = kb + 16384;
    int kv0 = kv_lo + t * 64;
#pragma unroll
    for (int i = 0; i < 4; ++i) {
      int L = i * 4096 + tid * 16;
      {
        int kv = L >> 8, cp = (L >> 4) & 15, cc = cp ^ (kv & 7);
        const uint8_t* src = (const uint8_t*)Kg + ((size_t)((b << 12) + kv0 + kv) << 8) + (cc << 4);
        gload16(src, kb + i * 4096 + w * 1024);
      }
      {
        int d = L >> 7, cp = (L >> 4) & 7, cc = cp ^ (d & 7);
        const uint8_t* src = (const uint8_t*)Vtg + ((size_t)(((b << 7) + d) << 12) + kv0 + (cc << 3)) * 2;
        gload16(src, vb + i * 4096 + w * 1024);
      }
    }
  };

  stage(0);
  __syncthreads();

  for (int t = 0; t < T; ++t) {
    if (t + 1 < T) stage(t + 1);
    const int kv0 = kv_lo + t * 64;
    if (kv0 <= q0w + 31) {
      uint8_t* kb = smem + (t & 1) * 32768;
      uint8_t* vb = kb + 16384;
      f32x4 sfr[4][2] = {};
#pragma unroll
      for (int kk = 0; kk < 4; ++kk) {
#pragma unroll
        for (int kvt = 0; kvt < 4; ++kvt) {
          int kvl = kvt * 16 + l15;
          bf16x8 kf = *(const bf16x8*)(kb + (kvl << 8) + (((kk * 4 + l16) ^ (kvl & 7)) << 4));
#pragma unroll
          for (int qt = 0; qt < 2; ++qt)
            sfr[kvt][qt] = mfma16(kf, qf[qt][kk], sfr[kvt][qt]);
        }
      }
      const bool need_mask = (kv0 + 63 > q0w);
      const float scale = 0.08838834764831845f;
#pragma unroll
      for (int qt = 0; qt < 2; ++qt) {
        const int q = q0w + qt * 16 + l15;
        float pvv[4][4];
        float tmax = -1e30f;
#pragma unroll
        for (int kvt = 0; kvt < 4; ++kvt)
#pragma unroll
          for (int r = 0; r < 4; ++r) {
            float sv = sfr[kvt][qt][r] * scale;
            if (need_mask) {
              int kv = kv0 + kvt * 16 + l16 * 4 + r;
              if (kv > q) sv = -1e30f;
            }
            pvv[kvt][r] = sv;
            tmax = fmaxf(tmax, sv);
          }
        tmax = fmaxf(tmax, __shfl_xor(tmax, 16));
        tmax = fmaxf(tmax, __shfl_xor(tmax, 32));
        float mnew = fmaxf(m_r[qt], tmax);
        float corr = __expf(m_r[qt] - mnew);
        m_r[qt] = mnew;
        float rs = 0.f;
#pragma unroll
        for (int kvt = 0; kvt < 4; ++kvt)
#pragma unroll
          for (int r = 0; r < 4; ++r) {
            float p = __expf(pvv[kvt][r] - mnew);
            pvv[kvt][r] = p;
            rs += p;
          }
        rs += __shfl_xor(rs, 16);
        rs += __shfl_xor(rs, 32);
        l_r[qt] = l_r[qt] * corr + rs;
        const int qrow = qt * 16 + l15;
#pragma unroll
        for (int kvt = 0; kvt < 4; ++kvt) {
          union { bf16 h[4]; uint32x2 u; } pk;
#pragma unroll
          for (int r = 0; r < 4; ++r) pk.h[r] = (bf16)pvv[kvt][r];
          int kv2 = kvt * 32 + l16 * 8;
          *(uint32x2*)(pb + qrow * 128 + ((((kv2 >> 4) ^ (qrow & 7)) << 4) | (kv2 & 15))) = pk.u;
        }
#pragma unroll
        for (int r = 0; r < 4; ++r) {
          float cr = __shfl(corr, l16 * 4 + r);
#pragma unroll
          for (int dt = 0; dt < 8; ++dt) o[qt][dt][r] *= cr;
        }
      }
      // PV
#pragma unroll
      for (int kvb = 0; kvb < 2; ++kvb) {
        bf16x8 pa[2];
#pragma unroll
        for (int qt = 0; qt < 2; ++qt) {
          int qrow = qt * 16 + l15;
          int kv2 = kvb * 64 + l16 * 16;
          pa[qt] = *(const bf16x8*)(pb + qrow * 128 + (((kv2 >> 4) ^ (qrow & 7)) << 4));
        }
#pragma unroll
        for (int dt = 0; dt < 8; ++dt) {
          int d = dt * 16 + l15;
          bf16x8 vf = *(const bf16x8*)(vb + (d << 7) + (((kvb * 4 + l16) ^ (d & 7)) << 4));
#pragma unroll
          for (int qt = 0; qt < 2; ++qt)
            o[qt][dt] = mfma16(pa[qt], vf, o[qt][dt]);
        }
      }
    }
    __syncthreads();
  }

  float* POb = PO + (size_t)((b * 32 + j) * 4 + c) * 16384;
#pragma unroll
  for (int qt = 0; qt < 2; ++qt)
#pragma unroll
    for (int dt = 0; dt < 8; ++dt)
#pragma unroll
      for (int r = 0; r < 4; ++r)
        POb[(w * 32 + qt * 16 + l16 * 4 + r) * 128 + dt * 16 + l15] = o[qt][dt][r];
  float* MLb = ML + (size_t)((b * 32 + j) * 4 + c) * 256;
  if (l16 == 0) {
#pragma unroll
    for (int qt = 0; qt < 2; ++qt) {
      MLb[w * 32 + qt * 16 + l15] = m_r[qt];
      MLb[128 + w * 32 + qt * 16 + l15] = l_r[qt];
    }
  }
}

// ---------------- combine partials ----------------
__global__ void k_combine(const float* __restrict__ PO, const float* __restrict__ ML,
                          float* __restrict__ out) {
  int blk = blockIdx.x;
  int b = blk >> 5, j = blk & 31;
  int nc = 1 + (j >> 3);
  int t = threadIdx.x;
  int q = t >> 1, half = t & 1;
  const float* MLb = ML + (size_t)(b * 32 + j) * 4 * 256;
  float mv[4], lv[4];
  float ms = -1e30f;
  for (int cc = 0; cc < nc; ++cc) {
    mv[cc] = MLb[cc * 256 + q];
    lv[cc] = MLb[cc * 256 + 128 + q];
    ms = fmaxf(ms, mv[cc]);
  }
  float wgt[4];
  float den = 0.f;
  for (int cc = 0; cc < nc; ++cc) { wgt[cc] = __expf(mv[cc] - ms); den += wgt[cc] * lv[cc]; }
  float inv = 1.f / den;
  const float* POb = PO + (size_t)(b * 32 + j) * 4 * 16384 + q * 128 + half * 64;
  float* ob = out + ((size_t)(b << 12) + j * 128 + q) * 128 + half * 64;
  for (int d = 0; d < 64; d += 4) {
    f32x4 a = {0.f, 0.f, 0.f, 0.f};
    for (int cc = 0; cc < nc; ++cc) {
      f32x4 v = *(const f32x4*)(POb + cc * 16384 + d);
      a += v * wgt[cc];
    }
    a *= inv;
    *(f32x4*)(ob + d) = a;
  }
}

extern "C" void kernel_launch(void* const* d_in, const int* in_sizes, int n_in,
                              void* d_out, int out_size, void* d_ws, size_t ws_size,
                              hipStream_t stream) {
  const float* x = (const float*)d_in[0];
  // d_in[1] = mask (causal; computed analytically)
  const float* sint = (const float*)d_in[2];
  const float* cost = (const float*)d_in[3];
  const float* Wq = (const float*)d_in[4];
  const float* Wk = (const float*)d_in[5];
  const float* Wv = (const float*)d_in[6];
  uint8_t* ws = (uint8_t*)d_ws;

  bf16* WA  = (bf16*)(ws + 0x0);        // 1.5 MB (fragment-ordered)
  bf16* Qg  = (bf16*)(ws + 0x180000);   // 4 MB
  bf16* Kg  = (bf16*)(ws + 0x580000);   // 4 MB
  bf16* Vtg = (bf16*)(ws + 0x980000);   // 4 MB
  float* PO = (float*)(ws + 0xD80000);  // 32 MB
  float* ML = (float*)(ws + 0x2D80000); // 0.5 MB
  float* out = (float*)d_out;

  hipLaunchKernelGGL(k_prep, dim3(192), dim3(256), 0, stream, Wq, Wk, Wv, WA);
  hipLaunchKernelGGL(k_proj, dim3(256), dim3(512), 0, stream, x, sint, cost, WA, Qg, Kg, Vtg);
  hipLaunchKernelGGL(k_attn, dim3(320), dim3(256), 0, stream, Qg, Kg, Vtg, PO, ML);
  hipLaunchKernelGGL(k_combine, dim3(128), dim3(256), 0, stream, PO, ML, out);
}